// Round 4
// baseline (62403.180 us; speedup 1.0000x reference)
//
#include <hip/hip_runtime.h>
#include <math.h>

// LSTMCharTagger: char biLSTM (both dirs scan forward, batch 8192, T=16)
// -> gather last char -> word biLSTM (batch 1, S=8192 sequential) -> logits -> log_softmax.
// R4: word_scan v4 — W pinned in VGPRs via asm (f32x4 w[8][4] = 128 regs),
// data-as-flag sync (sentinel 2.0f, |h|<1 so unreachable), zero LDS / zero
// barriers in the step loop, butterfly k-reduce, redundant per-lane cell.

#define SW 8192
#define TC 16
#define ECD 64
#define HCD 128
#define DWD 300
#define HWD 256
#define DIND 556
#define NTAGS 50

typedef float f32x4 __attribute__((ext_vector_type(4)));
typedef float f32x2 __attribute__((ext_vector_type(2)));

__device__ __forceinline__ float sigf(float x) { return 1.f / (1.f + expf(-x)); }

#define BM 64
#define BN 64
#define BK 16

// C[M,N] = A1@W1^T (+ A2@W2^T) + bias.  A1 rows optionally gathered via idx1.
__global__ __launch_bounds__(256) void gemm2(
    const float* __restrict__ A1, int lda1, const int* __restrict__ idx1,
    const float* __restrict__ W1, int ldw1, int K1,
    const float* __restrict__ A2, int lda2,
    const float* __restrict__ W2, int ldw2, int K2,
    const float* __restrict__ bias, float* __restrict__ C, int N, int ldc)
{
    __shared__ float As[BK][BM + 4];
    __shared__ float Ws[BK][BN + 4];
    const int tid = threadIdx.x;
    const int m0 = blockIdx.y * BM;
    const int n0 = blockIdx.x * BN;
    const int tx = tid & 15, ty = tid >> 4;
    const int lr = tid >> 2;
    const int lk4 = (tid & 3) << 2;

    float acc[4][4] = {};

    for (int part = 0; part < 2; ++part) {
        const int K = part ? K2 : K1;
        if (K == 0) continue;
        const float* A = part ? A2 : A1;
        const float* W = part ? W2 : W1;
        const int* idx = part ? (const int*)nullptr : idx1;
        const int lda = part ? lda2 : lda1;
        const int ldw = part ? ldw2 : ldw1;
        const int arow = idx ? idx[m0 + lr] : (m0 + lr);
        const float* Ab = A + (size_t)arow * lda;
        const int wrow = n0 + lr;
        const bool wv = wrow < N;
        const float* Wb = W + (size_t)(wv ? wrow : 0) * ldw;
        for (int k0 = 0; k0 < K; k0 += BK) {
            const int k = k0 + lk4;
            float4 av, bv;
            if (k + 3 < K) {
                av = *(const float4*)(Ab + k);
            } else {
                av.x = (k + 0 < K) ? Ab[k + 0] : 0.f;
                av.y = (k + 1 < K) ? Ab[k + 1] : 0.f;
                av.z = (k + 2 < K) ? Ab[k + 2] : 0.f;
                av.w = (k + 3 < K) ? Ab[k + 3] : 0.f;
            }
            if (wv && (k + 3 < K)) {
                bv = *(const float4*)(Wb + k);
            } else if (wv) {
                bv.x = (k + 0 < K) ? Wb[k + 0] : 0.f;
                bv.y = (k + 1 < K) ? Wb[k + 1] : 0.f;
                bv.z = (k + 2 < K) ? Wb[k + 2] : 0.f;
                bv.w = (k + 3 < K) ? Wb[k + 3] : 0.f;
            } else {
                bv.x = bv.y = bv.z = bv.w = 0.f;
            }
            As[lk4 + 0][lr] = av.x;
            As[lk4 + 1][lr] = av.y;
            As[lk4 + 2][lr] = av.z;
            As[lk4 + 3][lr] = av.w;
            Ws[lk4 + 0][lr] = bv.x;
            Ws[lk4 + 1][lr] = bv.y;
            Ws[lk4 + 2][lr] = bv.z;
            Ws[lk4 + 3][lr] = bv.w;
            __syncthreads();
#pragma unroll
            for (int kk = 0; kk < BK; ++kk) {
                const float4 a = *(const float4*)&As[kk][ty << 2];
                const float4 b = *(const float4*)&Ws[kk][tx << 2];
                acc[0][0] += a.x * b.x; acc[0][1] += a.x * b.y; acc[0][2] += a.x * b.z; acc[0][3] += a.x * b.w;
                acc[1][0] += a.y * b.x; acc[1][1] += a.y * b.y; acc[1][2] += a.y * b.z; acc[1][3] += a.y * b.w;
                acc[2][0] += a.z * b.x; acc[2][1] += a.z * b.y; acc[2][2] += a.z * b.z; acc[2][3] += a.z * b.w;
                acc[3][0] += a.w * b.x; acc[3][1] += a.w * b.y; acc[3][2] += a.w * b.z; acc[3][3] += a.w * b.w;
            }
            __syncthreads();
        }
    }
#pragma unroll
    for (int i = 0; i < 4; ++i) {
        const int m = m0 + (ty << 2) + i;
#pragma unroll
        for (int j = 0; j < 4; ++j) {
            const int n = n0 + (tx << 2) + j;
            if (n < N) C[(size_t)m * ldc + n] = acc[i][j] + (bias ? bias[n] : 0.f);
        }
    }
}

__global__ __launch_bounds__(256) void build_cidx(const int* __restrict__ char_ix,
                                                  int* __restrict__ cidx)
{
    const int id = blockIdx.x * 256 + threadIdx.x;   // t*SW + s
    const int t = id >> 13, s = id & (SW - 1);
    cidx[id] = char_ix[s * TC + t];
}

// gates [SW][512] (i,f,g,o x128); updates c,h [SW][128];
// o_out: write h at row stride 256 (or null); crepr: write h where char_len-1==t (or null).
__global__ __launch_bounds__(256) void lstm_cell_char(
    const float* __restrict__ gates, float* __restrict__ c, float* __restrict__ h,
    float* __restrict__ o_out, float* __restrict__ crepr,
    const int* __restrict__ char_len, int t)
{
    const int id = blockIdx.x * 256 + threadIdx.x;
    const int s = id >> 7, j = id & (HCD - 1);
    const float* g = gates + (size_t)s * 512;
    const float gi = g[j], gf = g[HCD + j], gg = g[2 * HCD + j], go = g[3 * HCD + j];
    const float cn = sigf(gf) * c[id] + sigf(gi) * tanhf(gg);
    const float hn = sigf(go) * tanhf(cn);
    c[id] = cn;
    h[id] = hn;
    if (o_out) o_out[(size_t)s * 256 + j] = hn;
    if (crepr && (char_len[s] - 1 == t)) crepr[(size_t)s * 256 + j] = hn;
}

__global__ __launch_bounds__(256) void fill_sentinel(float4* __restrict__ a, int n4)
{
    const int i = blockIdx.x * 256 + threadIdx.x;
    if (i < n4) a[i] = float4{2.f, 2.f, 2.f, 2.f};
}

// Word-LSTM scan v4. Grid = 16 blocks x 256 thr: d = blk>>3, bb = blk&7.
// Block owns h-slice [32*bb,32*bb+32) -> 128 gate rows (4 gates x 32).
// Thread (jp=tid>>4, cg=tid&15): rows {g*256+bb*32+jp*2+jo : g<4, jo<2},
// cols [cg*16, cg*16+16). W = 8x4 f32x4 = 128 VGPRs, pinned via asm.
// Sync: data-as-flag. out pre-filled with 2.0f (|h|<1 => unreachable);
// producers fire-and-forget 8B atomic stores; consumers poll own h words.
// Zero LDS, zero barriers in the step loop.
__global__ __launch_bounds__(256, 1) void word_scan(
    const float* __restrict__ G,     // [2][SW][1024] precomputed x@Wih^T + b
    const float* __restrict__ Whh,   // [2][1024][256]
    float* __restrict__ out)         // [SW][512]; fwd cols 0..255, bwd 256..511; sentinel-filled
{
    const int d = blockIdx.x >> 3;
    const int bb = blockIdx.x & 7;
    const int tid = threadIdx.x;
    const int jp = tid >> 4;        // 0..15: h-pair index
    const int cg = tid & 15;        // 0..15: k col-group

    // --- W into pinned registers (once) ---
    f32x4 w[8][4];
    {
        const float* wb = Whh + ((size_t)d << 18) + (size_t)(bb * 32 + jp * 2) * 256 + cg * 16;
#pragma unroll
        for (int g = 0; g < 4; ++g)
#pragma unroll
            for (int jo = 0; jo < 2; ++jo) {
                const float* row = wb + (size_t)(g * 256 + jo) * 256;
#pragma unroll
                for (int kq = 0; kq < 4; ++kq) {
                    w[g * 2 + jo][kq] = *(const f32x4*)(row + kq * 4);
                    asm volatile("" : "+v"(w[g * 2 + jo][kq]));
                }
            }
    }

    const float* Gd = G + ((size_t)d * SW * 1024);
    float* outd = out + (d << 8);
    const int tstart = d ? (SW - 1) : 0;
    const int tstep = d ? -1 : 1;
    const int gbase = bb * 32 + jp * 2;
    float c0 = 0.f, c1 = 0.f;

    f32x2 gq[4];
    if (cg == 0) {
#pragma unroll
        for (int g = 0; g < 4; ++g)
            gq[g] = *(const f32x2*)(Gd + (size_t)tstart * 1024 + g * 256 + gbase);
    }

    for (int it = 0; it < SW; ++it) {
        const int t = tstart + tstep * it;

        f32x4 hx[4];
        if (it) {
            const int tp = t - tstep;
            const unsigned long long* hp =
                (const unsigned long long*)(outd + (size_t)tp * 512 + cg * 16);
            unsigned long long hv[8];
            for (;;) {
                bool ok = true;
#pragma unroll
                for (int i = 0; i < 8; ++i) {
                    hv[i] = __hip_atomic_load(hp + i, __ATOMIC_RELAXED, __HIP_MEMORY_SCOPE_AGENT);
                    ok &= ((unsigned)hv[i] != 0x40000000u) &
                          ((unsigned)(hv[i] >> 32) != 0x40000000u);
                }
                if (ok) break;
            }
#pragma unroll
            for (int kq = 0; kq < 4; ++kq) {
                hx[kq][0] = __uint_as_float((unsigned)hv[2 * kq]);
                hx[kq][1] = __uint_as_float((unsigned)(hv[2 * kq] >> 32));
                hx[kq][2] = __uint_as_float((unsigned)hv[2 * kq + 1]);
                hx[kq][3] = __uint_as_float((unsigned)(hv[2 * kq + 1] >> 32));
            }
        } else {
#pragma unroll
            for (int kq = 0; kq < 4; ++kq) hx[kq] = f32x4{0.f, 0.f, 0.f, 0.f};
        }

        float acc[8];
#pragma unroll
        for (int r = 0; r < 8; ++r) {
            float a = 0.f;
#pragma unroll
            for (int kq = 0; kq < 4; ++kq) {
                a = fmaf(w[r][kq][0], hx[kq][0], a);
                a = fmaf(w[r][kq][1], hx[kq][1], a);
                a = fmaf(w[r][kq][2], hx[kq][2], a);
                a = fmaf(w[r][kq][3], hx[kq][3], a);
            }
            acc[r] = a;
        }
        if (cg == 0) {
#pragma unroll
            for (int g = 0; g < 4; ++g) {
                acc[g * 2 + 0] += gq[g][0];
                acc[g * 2 + 1] += gq[g][1];
            }
        }
#pragma unroll
        for (int m = 1; m < 16; m <<= 1)
#pragma unroll
            for (int r = 0; r < 8; ++r) acc[r] += __shfl_xor(acc[r], m);

        // cell update (redundant across cg lanes; identical fp -> consistent)
        c0 = sigf(acc[2]) * c0 + sigf(acc[0]) * tanhf(acc[4]);
        const float h0 = sigf(acc[6]) * tanhf(c0);
        c1 = sigf(acc[3]) * c1 + sigf(acc[1]) * tanhf(acc[5]);
        const float h1 = sigf(acc[7]) * tanhf(c1);

        if (cg == 0) {
            const unsigned long long pv =
                ((unsigned long long)__float_as_uint(h1) << 32) | __float_as_uint(h0);
            __hip_atomic_store((unsigned long long*)(outd + (size_t)t * 512 + gbase), pv,
                               __ATOMIC_RELAXED, __HIP_MEMORY_SCOPE_AGENT);
            if (it + 1 < SW) {
                const int tn = t + tstep;
#pragma unroll
                for (int g = 0; g < 4; ++g)
                    gq[g] = *(const f32x2*)(Gd + (size_t)tn * 1024 + g * 256 + gbase);
            }
        }
    }
}

__global__ __launch_bounds__(256) void logsoftmax50(const float* __restrict__ X,
                                                    float* __restrict__ Y)
{
    const int gw = (blockIdx.x * 256 + threadIdx.x) >> 6;
    const int lane = threadIdx.x & 63;
    if (gw >= SW) return;
    const float v = (lane < NTAGS) ? X[(size_t)gw * NTAGS + lane] : -3.4e38f;
    float m = v;
#pragma unroll
    for (int o = 32; o; o >>= 1) m = fmaxf(m, __shfl_xor(m, o));
    const float e = (lane < NTAGS) ? expf(v - m) : 0.f;
    float sum = e;
#pragma unroll
    for (int o = 32; o; o >>= 1) sum += __shfl_xor(sum, o);
    if (lane < NTAGS) Y[(size_t)gw * NTAGS + lane] = v - m - logf(sum);
}

extern "C" void kernel_launch(void* const* d_in, const int* in_sizes, int n_in,
                              void* d_out, int out_size, void* d_ws, size_t ws_size,
                              hipStream_t stream)
{
    const int* word_ix  = (const int*)d_in[0];
    const int* char_ix  = (const int*)d_in[1];
    const int* char_len = (const int*)d_in[2];
    const float* word_emb = (const float*)d_in[3];
    const float* char_emb = (const float*)d_in[4];
    const float* cW_ih0 = (const float*)d_in[5];
    const float* cW_hh0 = (const float*)d_in[6];
    const float* cb0    = (const float*)d_in[7];
    const float* cW_ih1 = (const float*)d_in[8];
    const float* cW_hh1 = (const float*)d_in[9];
    const float* cb1    = (const float*)d_in[10];
    const float* wW_ih0 = (const float*)d_in[11];
    const float* wW_hh0 = (const float*)d_in[12];
    const float* wb0    = (const float*)d_in[13];
    const float* wW_ih1 = (const float*)d_in[14];
    const float* wW_hh1 = (const float*)d_in[15];
    const float* wb1    = (const float*)d_in[16];
    const float* out_W  = (const float*)d_in[17];
    const float* out_b  = (const float*)d_in[18];
    float* Y = (float*)d_out;
    (void)in_sizes; (void)n_in; (void)out_size; (void)ws_size;

    char* p = (char*)d_ws;
    auto alloc = [&](size_t bytes) { char* q = p; p += (bytes + 255) & ~(size_t)255; return q; };
    float* ch_h  = (float*)alloc(4ull * SW * HCD * 4);         // [layer*2+dir][SW][HCD]
    float* ch_c  = (float*)alloc(4ull * SW * HCD * 4);
    const size_t zbytes = (size_t)(p - (char*)d_ws);           // zero: ch_h + ch_c
    float* gates = (float*)alloc(2ull * SW * 512 * 4);         // per-dir char gates / logits tmp
    float* o0s   = (float*)alloc((size_t)SW * 256 * 4);        // layer-0 output, current t only
    float* crepr = (float*)alloc((size_t)SW * 256 * 4);
    float* wG    = (float*)alloc(2ull * SW * 1024 * 4);        // word gate inputs (reused L0->L1)
    float* wo0   = (float*)alloc((size_t)SW * 512 * 4);
    float* wo1   = (float*)alloc((size_t)SW * 512 * 4);
    int*   cidx  = (int*)  alloc((size_t)TC * SW * 4);

    hipMemsetAsync(d_ws, 0, zbytes, stream);
    // sentinel-fill scan outputs (data-as-flag sync)
    fill_sentinel<<<(SW * 512 / 4 + 255) / 256, 256, 0, stream>>>((float4*)wo0, SW * 512 / 4);
    fill_sentinel<<<(SW * 512 / 4 + 255) / 256, 256, 0, stream>>>((float4*)wo1, SW * 512 / 4);
    build_cidx<<<TC * SW / 256, 256, 0, stream>>>(char_ix, cidx);

    // ---- char biLSTM: L0 and L1 interleaved per timestep (o0s is one-step ring) ----
    for (int t = 0; t < TC; ++t) {
        for (int d = 0; d < 2; ++d)
            gemm2<<<dim3(512 / BN, SW / BM), 256, 0, stream>>>(
                char_emb, ECD, cidx + t * SW, cW_ih0 + (size_t)d * 512 * ECD, ECD, ECD,
                ch_h + (size_t)d * SW * HCD, HCD, cW_hh0 + (size_t)d * 512 * HCD, HCD, HCD,
                cb0 + d * 512, gates + (size_t)d * SW * 512, 512, 512);
        for (int d = 0; d < 2; ++d)
            lstm_cell_char<<<SW * HCD / 256, 256, 0, stream>>>(
                gates + (size_t)d * SW * 512, ch_c + (size_t)d * SW * HCD,
                ch_h + (size_t)d * SW * HCD, o0s + d * HCD, nullptr, nullptr, t);
        for (int d = 0; d < 2; ++d)
            gemm2<<<dim3(512 / BN, SW / BM), 256, 0, stream>>>(
                o0s, 256, nullptr, cW_ih1 + (size_t)d * 512 * 256, 256, 256,
                ch_h + (size_t)(2 + d) * SW * HCD, HCD, cW_hh1 + (size_t)d * 512 * HCD, HCD, HCD,
                cb1 + d * 512, gates + (size_t)d * SW * 512, 512, 512);
        for (int d = 0; d < 2; ++d)
            lstm_cell_char<<<SW * HCD / 256, 256, 0, stream>>>(
                gates + (size_t)d * SW * 512, ch_c + (size_t)(2 + d) * SW * HCD,
                ch_h + (size_t)(2 + d) * SW * HCD, nullptr, crepr + d * HCD, char_len, t);
    }

    // ---- word biLSTM layer 0 ----
    for (int d = 0; d < 2; ++d)
        gemm2<<<dim3(1024 / BN, SW / BM), 256, 0, stream>>>(
            word_emb, DWD, word_ix, wW_ih0 + (size_t)d * 1024 * DIND, DIND, DWD,
            crepr, 256, wW_ih0 + (size_t)d * 1024 * DIND + DWD, DIND, 256,
            wb0 + d * 1024, wG + (size_t)d * SW * 1024, 1024, 1024);
    word_scan<<<16, 256, 0, stream>>>(wG, wW_hh0, wo0);

    // ---- word biLSTM layer 1 ----
    for (int d = 0; d < 2; ++d)
        gemm2<<<dim3(1024 / BN, SW / BM), 256, 0, stream>>>(
            wo0, 512, nullptr, wW_ih1 + (size_t)d * 1024 * 512, 512, 512,
            nullptr, 0, nullptr, 0, 0,
            wb1 + d * 1024, wG + (size_t)d * SW * 1024, 1024, 1024);
    word_scan<<<16, 256, 0, stream>>>(wG, wW_hh1, wo1);

    // ---- logits + log_softmax ----
    gemm2<<<dim3(1, SW / BM), 256, 0, stream>>>(
        wo1, 512, nullptr, out_W, 512, 512,
        nullptr, 0, nullptr, 0, 0,
        out_b, gates, NTAGS, NTAGS);
    logsoftmax50<<<SW * 64 / 256, 256, 0, stream>>>(gates, Y);
}

// Round 5
// 29192.935 us; speedup vs baseline: 2.1376x; 2.1376x over previous
//
#include <hip/hip_runtime.h>
#include <math.h>

// LSTMCharTagger: char biLSTM (both dirs scan forward, batch 8192, T=16)
// -> gather last char -> word biLSTM (batch 1, S=8192 sequential) -> logits -> log_softmax.
// R5: word_scan v5 — bf16-packed Whh (8 uint4/thread, 16 blocks/dir), wave0-only
// data-as-flag polling (sentinel 2.0f), LDS h-broadcast, fire-and-forget h stores.

#define SW 8192
#define TC 16
#define ECD 64
#define HCD 128
#define DWD 300
#define HWD 256
#define DIND 556
#define NTAGS 50
#define SENT 0x40000000u

__device__ __forceinline__ float sigf(float x) { return 1.f / (1.f + expf(-x)); }
__device__ __forceinline__ float blo(unsigned u) { return __uint_as_float(u << 16); }
__device__ __forceinline__ float bhi(unsigned u) { return __uint_as_float(u & 0xffff0000u); }
__device__ __forceinline__ unsigned short f2bf(float x) {
    unsigned u = __float_as_uint(x);
    return (unsigned short)((u + 0x7fffu + ((u >> 16) & 1u)) >> 16);
}

#define BM 64
#define BN 64
#define BK 16

// C[M,N] = A1@W1^T (+ A2@W2^T) + bias.  A1 rows optionally gathered via idx1.
__global__ __launch_bounds__(256) void gemm2(
    const float* __restrict__ A1, int lda1, const int* __restrict__ idx1,
    const float* __restrict__ W1, int ldw1, int K1,
    const float* __restrict__ A2, int lda2,
    const float* __restrict__ W2, int ldw2, int K2,
    const float* __restrict__ bias, float* __restrict__ C, int N, int ldc)
{
    __shared__ float As[BK][BM + 4];
    __shared__ float Ws[BK][BN + 4];
    const int tid = threadIdx.x;
    const int m0 = blockIdx.y * BM;
    const int n0 = blockIdx.x * BN;
    const int tx = tid & 15, ty = tid >> 4;
    const int lr = tid >> 2;
    const int lk4 = (tid & 3) << 2;

    float acc[4][4] = {};

    for (int part = 0; part < 2; ++part) {
        const int K = part ? K2 : K1;
        if (K == 0) continue;
        const float* A = part ? A2 : A1;
        const float* W = part ? W2 : W1;
        const int* idx = part ? (const int*)nullptr : idx1;
        const int lda = part ? lda2 : lda1;
        const int ldw = part ? ldw2 : ldw1;
        const int arow = idx ? idx[m0 + lr] : (m0 + lr);
        const float* Ab = A + (size_t)arow * lda;
        const int wrow = n0 + lr;
        const bool wv = wrow < N;
        const float* Wb = W + (size_t)(wv ? wrow : 0) * ldw;
        for (int k0 = 0; k0 < K; k0 += BK) {
            const int k = k0 + lk4;
            float4 av, bv;
            if (k + 3 < K) {
                av = *(const float4*)(Ab + k);
            } else {
                av.x = (k + 0 < K) ? Ab[k + 0] : 0.f;
                av.y = (k + 1 < K) ? Ab[k + 1] : 0.f;
                av.z = (k + 2 < K) ? Ab[k + 2] : 0.f;
                av.w = (k + 3 < K) ? Ab[k + 3] : 0.f;
            }
            if (wv && (k + 3 < K)) {
                bv = *(const float4*)(Wb + k);
            } else if (wv) {
                bv.x = (k + 0 < K) ? Wb[k + 0] : 0.f;
                bv.y = (k + 1 < K) ? Wb[k + 1] : 0.f;
                bv.z = (k + 2 < K) ? Wb[k + 2] : 0.f;
                bv.w = (k + 3 < K) ? Wb[k + 3] : 0.f;
            } else {
                bv.x = bv.y = bv.z = bv.w = 0.f;
            }
            As[lk4 + 0][lr] = av.x;
            As[lk4 + 1][lr] = av.y;
            As[lk4 + 2][lr] = av.z;
            As[lk4 + 3][lr] = av.w;
            Ws[lk4 + 0][lr] = bv.x;
            Ws[lk4 + 1][lr] = bv.y;
            Ws[lk4 + 2][lr] = bv.z;
            Ws[lk4 + 3][lr] = bv.w;
            __syncthreads();
#pragma unroll
            for (int kk = 0; kk < BK; ++kk) {
                const float4 a = *(const float4*)&As[kk][ty << 2];
                const float4 b = *(const float4*)&Ws[kk][tx << 2];
                acc[0][0] += a.x * b.x; acc[0][1] += a.x * b.y; acc[0][2] += a.x * b.z; acc[0][3] += a.x * b.w;
                acc[1][0] += a.y * b.x; acc[1][1] += a.y * b.y; acc[1][2] += a.y * b.z; acc[1][3] += a.y * b.w;
                acc[2][0] += a.z * b.x; acc[2][1] += a.z * b.y; acc[2][2] += a.z * b.z; acc[2][3] += a.z * b.w;
                acc[3][0] += a.w * b.x; acc[3][1] += a.w * b.y; acc[3][2] += a.w * b.z; acc[3][3] += a.w * b.w;
            }
            __syncthreads();
        }
    }
#pragma unroll
    for (int i = 0; i < 4; ++i) {
        const int m = m0 + (ty << 2) + i;
#pragma unroll
        for (int j = 0; j < 4; ++j) {
            const int n = n0 + (tx << 2) + j;
            if (n < N) C[(size_t)m * ldc + n] = acc[i][j] + (bias ? bias[n] : 0.f);
        }
    }
}

__global__ __launch_bounds__(256) void build_cidx(const int* __restrict__ char_ix,
                                                  int* __restrict__ cidx)
{
    const int id = blockIdx.x * 256 + threadIdx.x;   // t*SW + s
    const int t = id >> 13, s = id & (SW - 1);
    cidx[id] = char_ix[s * TC + t];
}

// gates [SW][512] (i,f,g,o x128); updates c,h [SW][128];
// o_out: write h at row stride 256 (or null); crepr: write h where char_len-1==t (or null).
__global__ __launch_bounds__(256) void lstm_cell_char(
    const float* __restrict__ gates, float* __restrict__ c, float* __restrict__ h,
    float* __restrict__ o_out, float* __restrict__ crepr,
    const int* __restrict__ char_len, int t)
{
    const int id = blockIdx.x * 256 + threadIdx.x;
    const int s = id >> 7, j = id & (HCD - 1);
    const float* g = gates + (size_t)s * 512;
    const float gi = g[j], gf = g[HCD + j], gg = g[2 * HCD + j], go = g[3 * HCD + j];
    const float cn = sigf(gf) * c[id] + sigf(gi) * tanhf(gg);
    const float hn = sigf(go) * tanhf(cn);
    c[id] = cn;
    h[id] = hn;
    if (o_out) o_out[(size_t)s * 256 + j] = hn;
    if (crepr && (char_len[s] - 1 == t)) crepr[(size_t)s * 256 + j] = hn;
}

__global__ __launch_bounds__(256) void fill_sentinel(float4* __restrict__ a, int n4)
{
    const int i = blockIdx.x * 256 + threadIdx.x;
    if (i < n4) a[i] = float4{2.f, 2.f, 2.f, 2.f};
}

// Pack Whh [2][1024][256] f32 -> bf16 chunks laid out exactly as word_scan consumes:
// P[((d*16+bb)*8 + i)*256 + tid] = uint4 of 8 bf16, thread tid=(r=tid>>2, cg=tid&3),
// global row (r>>4)*256 + bb*16 + (r&15), cols cg*64 + i*8 .. +8.
__global__ __launch_bounds__(256) void pack_whh(const float* __restrict__ Whh,
                                                uint4* __restrict__ P)
{
    const int id = blockIdx.x * 256 + threadIdx.x;   // 65536 total
    const int tid = id & 255;
    const int i = (id >> 8) & 7;
    const int bb = (id >> 11) & 15;
    const int d = id >> 15;
    const int r = tid >> 2, cg = tid & 3;
    const int grow = ((r >> 4) << 8) + (bb << 4) + (r & 15);
    const int col = (cg << 6) + (i << 3);
    const float* src = Whh + ((size_t)d << 18) + (size_t)grow * 256 + col;
    unsigned q[4];
#pragma unroll
    for (int m = 0; m < 4; ++m)
        q[m] = (unsigned)f2bf(src[2 * m]) | ((unsigned)f2bf(src[2 * m + 1]) << 16);
    P[id] = uint4{q[0], q[1], q[2], q[3]};
}

// Word-LSTM scan v5. Grid = 32 blocks x 256 thr: d = blk>>4, bb = blk&15.
// Block owns 64 gate rows (4 gates x 16 h-indices) -> 16 h outputs.
// Thread (r=tid>>2, cg=tid&3): 1 row x 64 cols; W = 8 uint4 bf16 (32 VGPRs).
// Sync: data-as-flag (sentinel 2.0f); wave0 polls 64x8B h-words, ds_writes the
// polled values to LDS (no re-read, no fence); producers fire-and-forget 4B stores.
__global__ __launch_bounds__(256, 1) void word_scan(
    const float* __restrict__ G,     // [2][SW][1024] precomputed x@Wih^T + b
    const uint4* __restrict__ Wp,    // packed bf16 Whh
    float* __restrict__ out)         // [SW][512]; fwd cols 0..255, bwd 256..511; sentinel-filled
{
    const int d = blockIdx.x >> 4;
    const int bb = blockIdx.x & 15;
    const int tid = threadIdx.x;
    const int l = tid & 63;
    const int wave = tid >> 6;
    const int r = tid >> 2;                      // local row 0..63
    const int cg = tid & 3;                      // col group
    const int g = r >> 4;                        // gate index (== wave, uniform)
    const int grow = (g << 8) + (bb << 4) + (r & 15);

    __shared__ float hl[4 * 68];                 // cg slices at stride 68 (bank-disjoint)
    __shared__ float gl[64];                     // activated gates: 4 gates x 16 j

    const uint4* wp = Wp + (((size_t)(d * 16 + bb)) << 11) + tid;  // + i*256
    const float* Gd = G + ((size_t)d * SW * 1024);
    const int dcol = d << 8;
    const int tstart = d ? (SW - 1) : 0;
    const int tstep = d ? -1 : 1;
    const int hdst = (l >> 5) * 68 + ((2 * l) & 63);
    float creg = 0.f;

    float gval = 0.f;
    if (cg == 0) gval = Gd[(size_t)tstart * 1024 + grow];

    for (int it = 0; it < SW; ++it) {
        const int t = tstart + tstep * it;

        // W chunks: loop-invariant loads; LICM keeps them resident, otherwise
        // they are issued here (before the poll) and overlap the handshake.
        uint4 wch[8];
#pragma unroll
        for (int i = 0; i < 8; ++i) wch[i] = wp[i << 8];

        if (wave == 0) {
            if (it) {
                const int tp = t - tstep;
                const unsigned long long* hp =
                    (const unsigned long long*)(out + (size_t)tp * 512 + dcol);
                unsigned long long v;
                do {
                    v = __hip_atomic_load(hp + l, __ATOMIC_RELAXED, __HIP_MEMORY_SCOPE_AGENT);
                } while (((unsigned)v == SENT) || ((unsigned)(v >> 32) == SENT));
                hl[hdst + 0] = __uint_as_float((unsigned)v);
                hl[hdst + 1] = __uint_as_float((unsigned)(v >> 32));
            } else {
                hl[hdst + 0] = 0.f;
                hl[hdst + 1] = 0.f;
            }
        }
        __syncthreads();                         // B1: hl ready

        const float4* hp4 = (const float4*)&hl[cg * 68];
        float acc = 0.f;
#pragma unroll
        for (int i = 0; i < 8; ++i) {
            const uint4 wv = wch[i];
            const float4 h0 = hp4[2 * i];
            const float4 h1 = hp4[2 * i + 1];
            acc = fmaf(blo(wv.x), h0.x, acc);
            acc = fmaf(bhi(wv.x), h0.y, acc);
            acc = fmaf(blo(wv.y), h0.z, acc);
            acc = fmaf(bhi(wv.y), h0.w, acc);
            acc = fmaf(blo(wv.z), h1.x, acc);
            acc = fmaf(bhi(wv.z), h1.y, acc);
            acc = fmaf(blo(wv.w), h1.z, acc);
            acc = fmaf(bhi(wv.w), h1.w, acc);
        }
        acc += __shfl_xor(acc, 1);
        acc += __shfl_xor(acc, 2);
        if (cg == 0) {
            const float s = acc + gval;
            gl[r] = (g == 2) ? tanhf(s) : sigf(s);   // wave-uniform branch
        }
        __syncthreads();                         // B2: gl ready, hl reads done

        if (tid < 16) {
            const float cn = gl[16 + tid] * creg + gl[tid] * gl[32 + tid];
            const float hn = gl[48 + tid] * tanhf(cn);
            creg = cn;
            __hip_atomic_store((unsigned*)(out + (size_t)t * 512 + dcol + (bb << 4) + tid),
                               __float_as_uint(hn),
                               __ATOMIC_RELAXED, __HIP_MEMORY_SCOPE_AGENT);
        }
        if (cg == 0 && it + 1 < SW)
            gval = Gd[(size_t)(t + tstep) * 1024 + grow];
    }
}

__global__ __launch_bounds__(256) void logsoftmax50(const float* __restrict__ X,
                                                    float* __restrict__ Y)
{
    const int gw = (blockIdx.x * 256 + threadIdx.x) >> 6;
    const int lane = threadIdx.x & 63;
    if (gw >= SW) return;
    const float v = (lane < NTAGS) ? X[(size_t)gw * NTAGS + lane] : -3.4e38f;
    float m = v;
#pragma unroll
    for (int o = 32; o; o >>= 1) m = fmaxf(m, __shfl_xor(m, o));
    const float e = (lane < NTAGS) ? expf(v - m) : 0.f;
    float sum = e;
#pragma unroll
    for (int o = 32; o; o >>= 1) sum += __shfl_xor(sum, o);
    if (lane < NTAGS) Y[(size_t)gw * NTAGS + lane] = v - m - logf(sum);
}

extern "C" void kernel_launch(void* const* d_in, const int* in_sizes, int n_in,
                              void* d_out, int out_size, void* d_ws, size_t ws_size,
                              hipStream_t stream)
{
    const int* word_ix  = (const int*)d_in[0];
    const int* char_ix  = (const int*)d_in[1];
    const int* char_len = (const int*)d_in[2];
    const float* word_emb = (const float*)d_in[3];
    const float* char_emb = (const float*)d_in[4];
    const float* cW_ih0 = (const float*)d_in[5];
    const float* cW_hh0 = (const float*)d_in[6];
    const float* cb0    = (const float*)d_in[7];
    const float* cW_ih1 = (const float*)d_in[8];
    const float* cW_hh1 = (const float*)d_in[9];
    const float* cb1    = (const float*)d_in[10];
    const float* wW_ih0 = (const float*)d_in[11];
    const float* wW_hh0 = (const float*)d_in[12];
    const float* wb0    = (const float*)d_in[13];
    const float* wW_ih1 = (const float*)d_in[14];
    const float* wW_hh1 = (const float*)d_in[15];
    const float* wb1    = (const float*)d_in[16];
    const float* out_W  = (const float*)d_in[17];
    const float* out_b  = (const float*)d_in[18];
    float* Y = (float*)d_out;
    (void)in_sizes; (void)n_in; (void)out_size; (void)ws_size;

    char* p = (char*)d_ws;
    auto alloc = [&](size_t bytes) { char* q = p; p += (bytes + 255) & ~(size_t)255; return q; };
    float* ch_h  = (float*)alloc(4ull * SW * HCD * 4);         // [layer*2+dir][SW][HCD]
    float* ch_c  = (float*)alloc(4ull * SW * HCD * 4);
    const size_t zbytes = (size_t)(p - (char*)d_ws);           // zero: ch_h + ch_c
    float* gates = (float*)alloc(2ull * SW * 512 * 4);         // per-dir char gates / logits tmp
    float* o0s   = (float*)alloc((size_t)SW * 256 * 4);        // layer-0 output, current t only
    float* crepr = (float*)alloc((size_t)SW * 256 * 4);
    float* wG    = (float*)alloc(2ull * SW * 1024 * 4);        // word gate inputs (reused L0->L1)
    float* wo0   = (float*)alloc((size_t)SW * 512 * 4);
    float* wo1   = (float*)alloc((size_t)SW * 512 * 4);
    uint4* Wp0   = (uint4*)alloc(65536ull * 16);               // packed bf16 wW_hh0
    uint4* Wp1   = (uint4*)alloc(65536ull * 16);               // packed bf16 wW_hh1
    int*   cidx  = (int*)  alloc((size_t)TC * SW * 4);

    hipMemsetAsync(d_ws, 0, zbytes, stream);
    fill_sentinel<<<(SW * 512 / 4 + 255) / 256, 256, 0, stream>>>((float4*)wo0, SW * 512 / 4);
    fill_sentinel<<<(SW * 512 / 4 + 255) / 256, 256, 0, stream>>>((float4*)wo1, SW * 512 / 4);
    pack_whh<<<256, 256, 0, stream>>>(wW_hh0, Wp0);
    pack_whh<<<256, 256, 0, stream>>>(wW_hh1, Wp1);
    build_cidx<<<TC * SW / 256, 256, 0, stream>>>(char_ix, cidx);

    // ---- char biLSTM: L0 and L1 interleaved per timestep (o0s is one-step ring) ----
    for (int t = 0; t < TC; ++t) {
        for (int d = 0; d < 2; ++d)
            gemm2<<<dim3(512 / BN, SW / BM), 256, 0, stream>>>(
                char_emb, ECD, cidx + t * SW, cW_ih0 + (size_t)d * 512 * ECD, ECD, ECD,
                ch_h + (size_t)d * SW * HCD, HCD, cW_hh0 + (size_t)d * 512 * HCD, HCD, HCD,
                cb0 + d * 512, gates + (size_t)d * SW * 512, 512, 512);
        for (int d = 0; d < 2; ++d)
            lstm_cell_char<<<SW * HCD / 256, 256, 0, stream>>>(
                gates + (size_t)d * SW * 512, ch_c + (size_t)d * SW * HCD,
                ch_h + (size_t)d * SW * HCD, o0s + d * HCD, nullptr, nullptr, t);
        for (int d = 0; d < 2; ++d)
            gemm2<<<dim3(512 / BN, SW / BM), 256, 0, stream>>>(
                o0s, 256, nullptr, cW_ih1 + (size_t)d * 512 * 256, 256, 256,
                ch_h + (size_t)(2 + d) * SW * HCD, HCD, cW_hh1 + (size_t)d * 512 * HCD, HCD, HCD,
                cb1 + d * 512, gates + (size_t)d * SW * 512, 512, 512);
        for (int d = 0; d < 2; ++d)
            lstm_cell_char<<<SW * HCD / 256, 256, 0, stream>>>(
                gates + (size_t)d * SW * 512, ch_c + (size_t)(2 + d) * SW * HCD,
                ch_h + (size_t)(2 + d) * SW * HCD, nullptr, crepr + d * HCD, char_len, t);
    }

    // ---- word biLSTM layer 0 ----
    for (int d = 0; d < 2; ++d)
        gemm2<<<dim3(1024 / BN, SW / BM), 256, 0, stream>>>(
            word_emb, DWD, word_ix, wW_ih0 + (size_t)d * 1024 * DIND, DIND, DWD,
            crepr, 256, wW_ih0 + (size_t)d * 1024 * DIND + DWD, DIND, 256,
            wb0 + d * 1024, wG + (size_t)d * SW * 1024, 1024, 1024);
    word_scan<<<32, 256, 0, stream>>>(wG, Wp0, wo0);

    // ---- word biLSTM layer 1 ----
    for (int d = 0; d < 2; ++d)
        gemm2<<<dim3(1024 / BN, SW / BM), 256, 0, stream>>>(
            wo0, 512, nullptr, wW_ih1 + (size_t)d * 1024 * 512, 512, 512,
            nullptr, 0, nullptr, 0, 0,
            wb1 + d * 1024, wG + (size_t)d * SW * 1024, 1024, 1024);
    word_scan<<<32, 256, 0, stream>>>(wG, Wp1, wo1);

    // ---- logits + log_softmax ----
    gemm2<<<dim3(1, SW / BM), 256, 0, stream>>>(
        wo1, 512, nullptr, out_W, 512, 512,
        nullptr, 0, nullptr, 0, 0,
        out_b, gates, NTAGS, NTAGS);
    logsoftmax50<<<SW * 64 / 256, 256, 0, stream>>>(gates, Y);
}